// Round 8
// baseline (174.692 us; speedup 1.0000x reference)
//
#include <hip/hip_runtime.h>
#include <hip/hip_bf16.h>

#define BB 4
#define CC 256
#define NN 4096
#define GG 8
#define SPLITS 4
#define TKV 32
#define ITERS (NN / SPLITS / TKV)

typedef unsigned char u8;
typedef unsigned short u16;
typedef unsigned int u32;
typedef __bf16 b16x8 __attribute__((ext_vector_type(8)));
typedef float f32x4 __attribute__((ext_vector_type(4)));
typedef u32 u32x4 __attribute__((ext_vector_type(4)));
typedef u32 u32x2 __attribute__((ext_vector_type(2)));
typedef u16 u16x4 __attribute__((ext_vector_type(4)));
typedef int i32x8 __attribute__((ext_vector_type(8)));

// softmax: P' = exp2(S_raw * QS - FMAX); QS = C^-0.5 * log2(e). FMAX=8 keeps
// P' inside e4m3's normal range. l,O scale-invariant.
#define QS 0.09016844005556021f
#define FMAX 8.0f

// bf16 fragment chunk (512 u16): elem(row,col32) = (quad(col32>>3)*16+row)*8+(col32&7)
// fp8 Q/K chunk (NEW, K=128-frag layout for mfma_scale 16x16x128):
//   per 16-row x 256-c: two 2048B chunks; addr(row,c) = (c>>7)*2048 + row*128 + (c&127)
//   lane (row=l15, quad) reads 32B at row*128 + quad*32  ->  k = quad*32 + j (one MX block)
// fp8 V superchunk (1024 B, 32 c x 32 kv):
//   addr(c,kv) = ((kv&31)>>3)*256 + (c&15)*16 + ((c>>4)&1)*8 + (kv&7)
// po (swapped-PV flash): per (split,b,ntile) chunk of 4096 u16:
//   u16 idx = (ct*64 + quad*16 + l15)*4 + r  ->  O[q=l15][c = ct*16 + quad*4 + r]

__device__ __forceinline__ u16 f2bf(float f) {
    u32 u = __builtin_bit_cast(u32, f);
    u = (u + 0x7FFFu + ((u >> 16) & 1u)) >> 16;
    return (u16)u;
}

__device__ __forceinline__ float bf2f(u16 h) {
    return __builtin_bit_cast(float, (u32)h << 16);
}

__device__ __forceinline__ u32 pack_bf2(float a, float b) {
    float2 f; f.x = a; f.y = b;
    __hip_bfloat162 h = __float22bfloat162_rn(f);
    u32 r;
    __builtin_memcpy(&r, &h, 4);
    return r;
}

__device__ __forceinline__ float exp2_raw(float x) {
#if __has_builtin(__builtin_amdgcn_exp2f)
    return __builtin_amdgcn_exp2f(x);
#else
    float r;
    asm("v_exp_f32 %0, %1" : "=v"(r) : "v"(x));
    return r;
#endif
}

__device__ __forceinline__ b16x8 ldfrag(const u16* p) {
    u32x4 v = *reinterpret_cast<const u32x4*>(p);
    return __builtin_bit_cast(b16x8, v);
}

__device__ __forceinline__ int pk_fp8x4(float a, float b, float c, float d) {
    int r = __builtin_amdgcn_cvt_pk_fp8_f32(a, b, 0, false);
    r = __builtin_amdgcn_cvt_pk_fp8_f32(c, d, r, true);
    return r;
}

__device__ __forceinline__ long as_long(u32x2 v) { return __builtin_bit_cast(long, v); }

__device__ __forceinline__ i32x8 cat8(u32x4 a, u32x4 b) {
    i32x8 r;
    r[0] = (int)a.x; r[1] = (int)a.y; r[2] = (int)a.z; r[3] = (int)a.w;
    r[4] = (int)b.x; r[5] = (int)b.y; r[6] = (int)b.z; r[7] = (int)b.w;
    return r;
}

// MX-scaled fp8 MFMA with unit scales (E8M0 127 = 1.0): plain fp8 GEMM at 2x rate.
__device__ __forceinline__ f32x4 mfma_qk128(i32x8 a, i32x8 b, f32x4 c) {
    return __builtin_amdgcn_mfma_scale_f32_16x16x128_f8f6f4(a, b, c, 0, 0, 0, 127, 0, 127);
}

// lane^16 within each 32-lane group (BitMode: xor=16, and=0x1F) — pure
// permutation through the LDS crossbar: zero bank conflicts.
__device__ __forceinline__ u32 swz16(u32 v) {
    return (u32)__builtin_amdgcn_ds_swizzle((int)v, 0x401F);
}

// v_permlane32_swap_b32: a_hi <-> b_lo. After: a=[a_lo,b_lo], b=[a_hi,b_hi].
// VALU-pipe op, no LDS involvement.
__device__ __forceinline__ void pls32(u32& a, u32& b) {
    asm("v_permlane32_swap_b32 %0, %1" : "+v"(a), "+v"(b));
}

typedef __attribute__((address_space(1))) const unsigned int* gas_p;
typedef __attribute__((address_space(3))) unsigned int* las_p;

__device__ __forceinline__ void g2l(const u8* g, u8* l) {
    __builtin_amdgcn_global_load_lds((gas_p)g, (las_p)l, 16, 0, 0);
}

__device__ __forceinline__ void g2l16(const u16* g, u16* l) {
    __builtin_amdgcn_global_load_lds((gas_p)g, (las_p)l, 16, 0, 0);
}

// ------- 2. Fold GN into QKV weights (stats inlined from gsum) + frag-major w_proj -------
__global__ void fold_w(const float* __restrict__ w_qkv, const float* __restrict__ w_proj,
                       const float* __restrict__ gamma, const float* __restrict__ beta,
                       const float* __restrict__ gsum,
                       u16* __restrict__ wqf, float* __restrict__ biasq,
                       u16* __restrict__ wpf) {
    int o = blockIdx.x;        // 0..767
    int b = blockIdx.y;        // 0..3
    int c = threadIdx.x;       // 0..255
    int g = c >> 5;
    const float inv = 1.f / ((CC / GG) * NN);
    float s  = gsum[(b * GG + g) * 2];
    float ss = gsum[(b * GG + g) * 2 + 1];
    float mu = s * inv;
    float rstd = rsqrtf(ss * inv - mu * mu + 1e-5f);
    float a  = gamma[c] * rstd;
    float bb = beta[c] - mu * a;
    float w = w_qkv[o * CC + c];
    size_t fe = ((size_t)((o >> 4) * 8 + (c >> 5)) * 64 + ((c & 31) >> 3) * 16 + (o & 15)) * 8 + (c & 7);
    wqf[(size_t)b * 768 * CC + fe] = f2bf(w * a);
    float part = w * bb;
    #pragma unroll
    for (int off = 32; off; off >>= 1) part += __shfl_down(part, off, 64);
    __shared__ float red[4];
    if ((threadIdx.x & 63) == 0) red[threadIdx.x >> 6] = part;
    __syncthreads();
    if (threadIdx.x == 0) biasq[b * 768 + o] = red[0] + red[1] + red[2] + red[3];
    if (b == 0 && o < CC) {
        float wp = w_proj[o * CC + c];
        wpf[fe] = f2bf(wp);
    }
}

// ---- 3. x [B][C][N] fp32 -> xt_frag bf16 (float4 loads); fused GN partial sums ----
__global__ void transpose_x(const float* __restrict__ x, u16* __restrict__ xtf,
                            float* __restrict__ gsum) {
    __shared__ float tile[64][65];
    __shared__ float red[4][4];
    int n0 = blockIdx.x * 64, c0 = blockIdx.y * 64, b = blockIdx.z;
    int t = threadIdx.x;
    int c4 = (t & 15) * 4;        // col base within 64-n tile
    int r0 = t >> 4;              // 0..15
    const float* xp = x + (size_t)b * CC * NN;
    float s0 = 0.f, ss0 = 0.f, s1 = 0.f, ss1 = 0.f;
    #pragma unroll
    for (int i = 0; i < 4; ++i) {
        int row = i * 16 + r0;
        float4 v = *reinterpret_cast<const float4*>(&xp[(size_t)(c0 + row) * NN + n0 + c4]);
        tile[row][c4 + 0] = v.x; tile[row][c4 + 1] = v.y;
        tile[row][c4 + 2] = v.z; tile[row][c4 + 3] = v.w;
        float s = v.x + v.y + v.z + v.w;
        float q = v.x * v.x + v.y * v.y + v.z * v.z + v.w * v.w;
        if (i < 2) { s0 += s; ss0 += q; } else { s1 += s; ss1 += q; }
    }
    #pragma unroll
    for (int off = 32; off; off >>= 1) {
        s0 += __shfl_down(s0, off, 64); ss0 += __shfl_down(ss0, off, 64);
        s1 += __shfl_down(s1, off, 64); ss1 += __shfl_down(ss1, off, 64);
    }
    int wid = t >> 6;
    if ((t & 63) == 0) { red[wid][0] = s0; red[wid][1] = ss0; red[wid][2] = s1; red[wid][3] = ss1; }
    __syncthreads();
    if (t < 2) {
        float s  = red[0][t * 2] + red[1][t * 2] + red[2][t * 2] + red[3][t * 2];
        float ss = red[0][t * 2 + 1] + red[1][t * 2 + 1] + red[2][t * 2 + 1] + red[3][t * 2 + 1];
        int g = (c0 >> 5) + t;
        atomicAdd(&gsum[(b * GG + g) * 2], s);
        atomicAdd(&gsum[(b * GG + g) * 2 + 1], ss);
    }
    int nl = t >> 2;
    int cbq = t & 3;
    int l15 = nl & 15;
    int ntile = (n0 >> 4) + (nl >> 4);
    int kk = (c0 >> 5) + (cbq >> 1);
    u16* ob = xtf + (size_t)b * NN * CC;
    #pragma unroll
    for (int g = 0; g < 4; ++g) {
        int quad = (cbq & 1) * 2 + (g >> 1);
        int j0 = (g & 1) * 4;
        u16x4 v;
        v.x = f2bf(tile[cbq * 16 + g * 4 + 0][nl]);
        v.y = f2bf(tile[cbq * 16 + g * 4 + 1][nl]);
        v.z = f2bf(tile[cbq * 16 + g * 4 + 2][nl]);
        v.w = f2bf(tile[cbq * 16 + g * 4 + 3][nl]);
        *reinterpret_cast<u16x4*>(ob + ((size_t)(ntile * 8 + kk) * 64 + quad * 16 + l15) * 8 + j0) = v;
    }
}

// ------- 4. QKV GEMM: LDS-staged B-tile, 128 o-rows/block -> fp8 q/k (K128-frag) + v -------
__global__ void __launch_bounds__(256) qkv_gemm(const u16* __restrict__ wqf,
                                                const float* __restrict__ biasq,
                                                const u16* __restrict__ xtf,
                                                u8* __restrict__ qtf, u8* __restrict__ ktf,
                                                u8* __restrict__ vvf) {
    __shared__ u16 bx[16384];     // 64 n x 256 c bf16 frag tile, 32 KB contiguous
    int b = blockIdx.z;
    int o0 = blockIdx.y * 128;    // 0,128,...,640 — never spans Q/K/V boundary
    int n0 = blockIdx.x * 64;
    int lane = threadIdx.x & 63, w = threadIdx.x >> 6;
    int l15 = lane & 15, quad = lane >> 4;
    const u16* Bg = xtf + (size_t)b * NN * CC + (size_t)n0 * 256;
    #pragma unroll
    for (int j = 0; j < 8; ++j) {
        int c = w * 8 + j;
        g2l16(Bg + (size_t)c * 512 + lane * 8, bx + (size_t)c * 512 + lane * 8);
    }
    __syncthreads();

    const u16* A = wqf + (size_t)b * 768 * CC;
    f32x4 acc[2][4] = {};
    #pragma unroll
    for (int kk = 0; kk < 8; ++kk) {
        b16x8 af[2];
        #pragma unroll
        for (int t = 0; t < 2; ++t) {
            int otile = (o0 >> 4) + w * 2 + t;
            af[t] = ldfrag(A + (size_t)(otile * 8 + kk) * 512 + lane * 8);
        }
        #pragma unroll
        for (int nt = 0; nt < 4; ++nt) {
            b16x8 bf = ldfrag(bx + (size_t)(nt * 8 + kk) * 512 + lane * 8);
            acc[0][nt] = __builtin_amdgcn_mfma_f32_16x16x32_bf16(af[0], bf, acc[0][nt], 0, 0, 0);
            acc[1][nt] = __builtin_amdgcn_mfma_f32_16x16x32_bf16(af[1], bf, acc[1][nt], 0, 0, 0);
        }
    }
    #pragma unroll
    for (int t = 0; t < 2; ++t) {
        int o_base = o0 + (w * 2 + t) * 16 + quad * 4;
        float bias[4];
        #pragma unroll
        for (int r = 0; r < 4; ++r) bias[r] = biasq[b * 768 + o_base + r];
        if (o0 < 512) {
            int oloc = (o0 < 256) ? o_base : (o_base - 256);
            u8* dst = ((o0 < 256) ? qtf : ktf) + (size_t)b * NN * CC;
            #pragma unroll
            for (int nt = 0; nt < 4; ++nt) {
                int n = n0 + nt * 16 + l15;
                int pk = pk_fp8x4(acc[t][nt][0] + bias[0], acc[t][nt][1] + bias[1],
                                  acc[t][nt][2] + bias[2], acc[t][nt][3] + bias[3]);
                // K128-frag layout: addr(row=n, c=oloc) = chunk(n>>4)*4096 + (c>>7)*2048
                //                                        + (n&15)*128 + (c&127)
                size_t addr = (size_t)(n >> 4) * 4096 + (size_t)(oloc >> 7) * 2048
                            + (size_t)(n & 15) * 128 + (oloc & 127);
                *reinterpret_cast<u32*>(dst + addr) = (u32)pk;
            }
        } else {
            int cb = o_base - 512;
            u8* dst = vvf + (size_t)b * NN * CC;
            #pragma unroll
            for (int nt = 0; nt < 4; ++nt) {
                int kv = n0 + nt * 16 + l15;
                int pk = pk_fp8x4(acc[t][nt][0] + bias[0], acc[t][nt][1] + bias[1],
                                  acc[t][nt][2] + bias[2], acc[t][nt][3] + bias[3]);
                size_t base = (size_t)((kv >> 5) * 8 + (cb >> 5)) * 1024
                            + ((kv & 31) >> 3) * 256 + ((cb >> 4) & 1) * 8 + (kv & 7);
                #pragma unroll
                for (int r = 0; r < 4; ++r)
                    dst[base + ((cb & 15) + r) * 16] = (u8)(pk >> (r * 8));
            }
        }
    }
}

// ----- 5. Flash: QK^T via MX-scaled K=128 MFMA (unit scales, 2x fp8 rate): 4 MFMAs -----
// ----- per 32-kv iter instead of 16 — attacks the measured issue-saturation.       -----
// ----- C/D layout unchanged -> softmax/exchange/PV(K=32)/po all verbatim from R7.  -----
// ----- TKV=32, 4-wave blocks, 4 barrier groups/CU as verified in R7.               -----
__global__ void __launch_bounds__(256, 4) flash(const u8* __restrict__ qtf,
                                                const u8* __restrict__ ktf,
                                                const u8* __restrict__ vvf,
                                                u16* __restrict__ po,
                                                float* __restrict__ lp) {
    __shared__ u8 kbuf[2][8192];
    __shared__ u8 vbuf[2][8192];
    int lin = blockIdx.x;
    int chunk = lin & 15;
    int nblk = lin >> 4;                  // 0..63
    int b = chunk >> 2, sp = chunk & 3;
    int lane = threadIdx.x & 63, w = threadIdx.x >> 6;   // w 0..3
    int l15 = lane & 15, quad = lane >> 4;
    int ntile = nblk * 4 + w;             // this wave's 16 q rows (0..255)
    const u8* kb8 = ktf + (size_t)b * NN * CC;
    const u8* vb8 = vvf + (size_t)b * NN * CC;
    const bool qodd = (quad & 1) != 0;

    // Q: two K=128 B-frags (col=q=l15, k=c=quad*32+j within each 128-c chunk)
    i32x8 qop[2];
    {
        const u8* qp = qtf + (size_t)b * NN * CC + (size_t)ntile * 4096
                     + (size_t)l15 * 128 + (size_t)quad * 32;
        u32x4 q0 = *reinterpret_cast<const u32x4*>(qp);
        u32x4 q1 = *reinterpret_cast<const u32x4*>(qp + 16);
        u32x4 q2 = *reinterpret_cast<const u32x4*>(qp + 2048);
        u32x4 q3 = *reinterpret_cast<const u32x4*>(qp + 2048 + 16);
        qop[0] = cat8(q0, q1);
        qop[1] = cat8(q2, q3);
    }

    f32x4 acco[16] = {};
    f32x4 accs[2];
    const f32x4 zz = {0.f, 0.f, 0.f, 0.f};
    float lsum = 0.f;

    const int m_beg = sp * (NN / SPLITS);

    auto stage_k = [&](int buf, int m0) {
        const u8* ks = kb8 + ((size_t)m0 << 8);
        #pragma unroll
        for (int j = 0; j < 2; ++j) {
            int idx = w * 2 + j;          // 0..7 (8 KB tile)
            g2l(ks + idx * 1024 + lane * 16, &kbuf[buf][idx * 1024]);
        }
    };
    auto stage_v = [&](int buf, int m0) {
        const u8* vs = vb8 + ((size_t)m0 << 8);
        #pragma unroll
        for (int j = 0; j < 2; ++j) {
            int idx = w * 2 + j;          // 0..7 (8 KB tile)
            g2l(vs + idx * 1024 + lane * 16, &vbuf[buf][idx * 1024]);
        }
    };
    // QK over 32 kv: 2 kv-tiles x 2 K=128 MFMAs (A = K-frag, B = Q-frag, swapped)
    auto qk_tile = [&](const u8* kc) {
        __builtin_amdgcn_s_setprio(1);
        const u8* kp = kc + (size_t)l15 * 128 + (size_t)quad * 32;
        #pragma unroll
        for (int mm = 0; mm < 2; ++mm) {
            f32x4 acc = zz;
            #pragma unroll
            for (int cc = 0; cc < 2; ++cc) {
                const u8* p = kp + mm * 4096 + cc * 2048;
                u32x4 k0 = *reinterpret_cast<const u32x4*>(p);
                u32x4 k1 = *reinterpret_cast<const u32x4*>(p + 16);
                acc = mfma_qk128(cat8(k0, k1), qop[cc], acc);
            }
            accs[mm] = acc;
        }
        __builtin_amdgcn_s_setprio(0);
    };
    auto exch = [&](int pa, int pb) -> long {
        u32 a = (u32)pa, bm = (u32)pb;
        u32 ax = swz16(a), bx = swz16(bm);
        pls32(a, bm);    // a=[a_lo,b_lo], bm=[a_hi,b_hi]
        pls32(ax, bx);   // ax=[ax_lo,bx_lo], bx=[ax_hi,bx_hi]
        u32 blo = qodd ? bx : a;
        u32 bhi = qodd ? bm : ax;
        return as_long(u32x2{blo, bhi});   // P^T frag: col=q=l15, k=kv=quad*8+j
    };

    // prologue: K0->k0, V0->v0, K1->k1; QK(0) in its own barrier window
    stage_k(0, m_beg);
    stage_v(0, m_beg);
    stage_k(1, m_beg + TKV);
    __syncthreads();
    qk_tile(&kbuf[0][0]);
    __syncthreads();

    for (int it = 0; it < ITERS; ++it) {
        int cur = it & 1;
        // softmax of S_it (accs dead after pk extraction)
        int pk[2];
        #pragma unroll
        for (int mm = 0; mm < 2; ++mm) {
            float e0 = exp2_raw(fmaf(accs[mm][0], QS, -FMAX));
            float e1 = exp2_raw(fmaf(accs[mm][1], QS, -FMAX));
            float e2 = exp2_raw(fmaf(accs[mm][2], QS, -FMAX));
            float e3 = exp2_raw(fmaf(accs[mm][3], QS, -FMAX));
            lsum += (e0 + e1) + (e2 + e3);
            pk[mm] = pk_fp8x4(e0, e1, e2, e3);
        }
        // QK(it+1): MFMA pipe refills while exchange/stage below issues
        if (it + 1 < ITERS) qk_tile(&kbuf[cur ^ 1][0]);
        // prefetch: K two tiles ahead, V one tile ahead
        if (it + 2 < ITERS) stage_k(cur, m_beg + (it + 2) * TKV);
        if (it + 1 < ITERS) stage_v(cur ^ 1, m_beg + (it + 1) * TKV);
        // exchange + PV(it)  (K=32 fp8 path, unchanged)
        const u8* vc = &vbuf[cur][0];
        long bop = exch(pk[0], pk[1]);
        __builtin_amdgcn_s_setprio(1);
        #pragma unroll
        for (int c2 = 0; c2 < 8; ++c2) {
            u32x4 vf = *reinterpret_cast<const u32x4*>(vc + (size_t)c2 * 1024 + lane * 16);
            acco[c2 * 2]     = __builtin_amdgcn_mfma_f32_16x16x32_fp8_fp8(
                as_long(u32x2{vf.x, vf.y}), bop, acco[c2 * 2], 0, 0, 0);
            acco[c2 * 2 + 1] = __builtin_amdgcn_mfma_f32_16x16x32_fp8_fp8(
                as_long(u32x2{vf.z, vf.w}), bop, acco[c2 * 2 + 1], 0, 0, 0);
        }
        __builtin_amdgcn_s_setprio(0);
        __syncthreads();
    }
    // epilogue: same store addresses; semantic O[q=l15][c = ct*16 + quad*4 + r]
    u16* pochunk = po + ((size_t)(sp * BB + b) * 256 + ntile) * 4096;
    #pragma unroll
    for (int ct = 0; ct < 16; ++ct) {
        u32x2 st;
        st.x = pack_bf2(acco[ct][0], acco[ct][1]);
        st.y = pack_bf2(acco[ct][2], acco[ct][3]);
        *reinterpret_cast<u32x2*>(pochunk + (size_t)(ct * 64 + quad * 16 + l15) * 4) = st;
    }
    // l[q]: quad-partitioned partials -> butterfly over quads
    lsum += __shfl_xor(lsum, 16, 64);
    lsum += __shfl_xor(lsum, 32, 64);
    if (lane < 16)
        lp[(size_t)(sp * BB + b) * NN + ntile * 16 + l15] = lsum;
}

// ------- 6. Fused proj: combine po/lp -> LDS bf16 frags, GEMM, + bias + residual -------
__global__ void __launch_bounds__(512) proj(const u16* __restrict__ wpf,
                                            const float* __restrict__ b_proj,
                                            const u16* __restrict__ po,
                                            const float* __restrict__ lp,
                                            const float* __restrict__ x,
                                            float* __restrict__ out) {
    __shared__ u16 bO[16384];      // 64 n x 256 c bf16 frag-major (local ntile-major)
    int b = blockIdx.y, n0 = blockIdx.x * 64;
    int t = threadIdx.x;
    // phase 1: combine 4 splits of po into bO (po layout: O[q=l15][c=ct*16+quad*4+r])
    {
        int u = t & 127, ntl = t >> 7;    // ntl 0..3
        int nb = (n0 >> 4) + ntl;
        int a = u & 7;                    // n pair: rows 2a, 2a+1 within 16-tile
        int cblk = u >> 3;                // 0..15 -> c = cblk*16 + cc
        float accn[2][16] = {};
        float lsum2[2] = {};
        #pragma unroll
        for (int s = 0; s < SPLITS; ++s) {
            const u16* src = po + (((size_t)(s * BB + b) * 256 + nb) * 4096)
                           + cblk * 256 + a * 8;
            #pragma unroll
            for (int q4 = 0; q4 < 4; ++q4) {
                u16 s16[8];
                *reinterpret_cast<u32x4*>(s16) = *reinterpret_cast<const u32x4*>(src + q4 * 64);
                #pragma unroll
                for (int k = 0; k < 8; ++k)
                    accn[k >> 2][q4 * 4 + (k & 3)] += bf2f(s16[k]);
            }
            lsum2[0] += lp[(size_t)(s * BB + b) * NN + nb * 16 + a * 2];
            lsum2[1] += lp[(size_t)(s * BB + b) * NN + nb * 16 + a * 2 + 1];
        }
        #pragma unroll
        for (int nsel = 0; nsel < 2; ++nsel) {
            float inv = 1.f / lsum2[nsel];
            int row = a * 2 + nsel;
            #pragma unroll
            for (int h = 0; h < 2; ++h) {
                u16 outv[8];
                #pragma unroll
                for (int j = 0; j < 8; ++j) outv[j] = f2bf(accn[nsel][h * 8 + j] * inv);
                int kk = cblk >> 1, quad_f = (cblk & 1) * 2 + h;
                size_t off = ((size_t)(ntl * 8 + kk) * 64 + quad_f * 16 + row) * 8;
                *reinterpret_cast<u32x4*>(bO + off) = *reinterpret_cast<const u32x4*>(outv);
            }
        }
    }
    __syncthreads();
    // phase 2: GEMM — 8 waves x 2 o-tiles = full 256 outputs
    int lane = t & 63, w = t >> 6;
    int l15 = lane & 15, quad = lane >> 4;
    f32x4 acc2[2][4] = {};
    #pragma unroll
    for (int kk = 0; kk < 8; ++kk) {
        b16x8 af[2];
        #pragma unroll
        for (int tt = 0; tt < 2; ++tt) {
            int otile = w * 2 + tt;
            af[tt] = ldfrag(wpf + (size_t)(otile * 8 + kk) * 512 + lane * 8);
        }
        #pragma unroll
        for (int nt = 0; nt < 4; ++nt) {
            b16x8 bf = ldfrag(bO + (size_t)(nt * 8 + kk) * 512 + lane * 8);
            acc2[0][nt] = __builtin_amdgcn_mfma_f32_16x16x32_bf16(af[0], bf, acc2[0][nt], 0, 0, 0);
            acc2[1][nt] = __builtin_amdgcn_mfma_f32_16x16x32_bf16(af[1], bf, acc2[1][nt], 0, 0, 0);
        }
    }
    #pragma unroll
    for (int tt = 0; tt < 2; ++tt) {
        int o_base = (w * 2 + tt) * 16 + quad * 4;
        #pragma unroll
        for (int nt = 0; nt < 4; ++nt) {
            int n = n0 + nt * 16 + l15;
            #pragma unroll
            for (int r = 0; r < 4; ++r) {
                int o = o_base + r;
                size_t idx = ((size_t)(b * CC + o)) * NN + n;
                out[idx] = acc2[tt][nt][r] + b_proj[o] + x[idx];
            }
        }
    }
}

extern "C" void kernel_launch(void* const* d_in, const int* in_sizes, int n_in,
                              void* d_out, int out_size, void* d_ws, size_t ws_size,
                              hipStream_t stream) {
    const float* x      = (const float*)d_in[0];
    const float* gamma  = (const float*)d_in[1];
    const float* beta   = (const float*)d_in[2];
    const float* w_qkv  = (const float*)d_in[3];
    const float* w_proj = (const float*)d_in[4];
    const float* b_proj = (const float*)d_in[5];
    float* out = (float*)d_out;

    char* p = (char*)d_ws;
    float* gsum  = (float*)p; p += 256;
    float* biasq = (float*)p; p += (size_t)BB * 768 * sizeof(float);
    u16* wqf = (u16*)p; p += (size_t)BB * 768 * CC * 2;
    u16* wpf = (u16*)p; p += (size_t)CC * CC * 2;
    u16* xtf = (u16*)p; p += (size_t)BB * NN * CC * 2;
    u8* qtf8 = (u8*)p; p += (size_t)BB * NN * CC;
    u8* ktf8 = (u8*)p; p += (size_t)BB * NN * CC;
    u8* vvf8 = (u8*)p; p += (size_t)BB * NN * CC;
    u16* po = (u16*)p; p += (size_t)SPLITS * BB * NN * CC * 2;
    float* lp = (float*)p; p += (size_t)SPLITS * BB * NN * sizeof(float);
    (void)ws_size; (void)in_sizes; (void)n_in; (void)out_size;

    (void)hipMemsetAsync(gsum, 0, BB * GG * 2 * sizeof(float), stream);
    transpose_x<<<dim3(NN / 64, CC / 64, BB), 256, 0, stream>>>(x, xtf, gsum);
    fold_w<<<dim3(768, BB), 256, 0, stream>>>(w_qkv, w_proj, gamma, beta, gsum, wqf, biasq, wpf);
    qkv_gemm<<<dim3(NN / 64, 6, BB), 256, 0, stream>>>(wqf, biasq, xtf, qtf8, ktf8, vvf8);
    flash<<<(NN / 64) * SPLITS * BB, 256, 0, stream>>>(qtf8, ktf8, vvf8, po, lp);
    proj<<<dim3(NN / 64, BB), 512, 0, stream>>>(wpf, b_proj, po, lp, x, out);
}

// Round 9
// 171.490 us; speedup vs baseline: 1.0187x; 1.0187x over previous
//
#include <hip/hip_runtime.h>
#include <hip/hip_bf16.h>

#define BB 4
#define CC 256
#define NN 4096
#define GG 8
#define SPLITS 4
#define TKV 32
#define ITERS (NN / SPLITS / TKV)

typedef unsigned char u8;
typedef unsigned short u16;
typedef unsigned int u32;
typedef __bf16 b16x8 __attribute__((ext_vector_type(8)));
typedef float f32x4 __attribute__((ext_vector_type(4)));
typedef u32 u32x4 __attribute__((ext_vector_type(4)));
typedef u32 u32x2 __attribute__((ext_vector_type(2)));
typedef u16 u16x4 __attribute__((ext_vector_type(4)));
typedef int i32x8 __attribute__((ext_vector_type(8)));

// softmax: P' = exp2(S_raw * QS - FMAX); QS = C^-0.5 * log2(e). FMAX=8 keeps
// P' inside e4m3's normal range. l,O scale-invariant.
#define QS 0.09016844005556021f
#define FMAX 8.0f

// bf16 fragment chunk (512 u16): elem(row,col32) = (quad(col32>>3)*16+row)*8+(col32&7)
// fp8 Q/K chunk (K=128-frag layout for mfma_scale 16x16x128, XOR-SWIZZLED):
//   per 16-row x 256-c: two 2048B chunks;
//   addr(row,c) = (c>>7)*2048 + row*128 + ((c&127) ^ ((row&7)<<4))
//   lane (row=l15, quad) reads 2x16B at (quad*32 {+16}) ^ ((l15&7)<<4)
//   -> k = quad*32 + j (one MX block/lane); swizzle spreads the 128B-stride
//   reads across all 8 bank slots (16-way conflict without it — R8 lesson).
// fp8 V superchunk (1024 B, 32 c x 32 kv):
//   addr(c,kv) = ((kv&31)>>3)*256 + (c&15)*16 + ((c>>4)&1)*8 + (kv&7)
// po (swapped-PV flash): per (split,b,ntile) chunk of 4096 u16:
//   u16 idx = (ct*64 + quad*16 + l15)*4 + r  ->  O[q=l15][c = ct*16 + quad*4 + r]

__device__ __forceinline__ u16 f2bf(float f) {
    u32 u = __builtin_bit_cast(u32, f);
    u = (u + 0x7FFFu + ((u >> 16) & 1u)) >> 16;
    return (u16)u;
}

__device__ __forceinline__ float bf2f(u16 h) {
    return __builtin_bit_cast(float, (u32)h << 16);
}

__device__ __forceinline__ u32 pack_bf2(float a, float b) {
    float2 f; f.x = a; f.y = b;
    __hip_bfloat162 h = __float22bfloat162_rn(f);
    u32 r;
    __builtin_memcpy(&r, &h, 4);
    return r;
}

__device__ __forceinline__ float exp2_raw(float x) {
#if __has_builtin(__builtin_amdgcn_exp2f)
    return __builtin_amdgcn_exp2f(x);
#else
    float r;
    asm("v_exp_f32 %0, %1" : "=v"(r) : "v"(x));
    return r;
#endif
}

__device__ __forceinline__ b16x8 ldfrag(const u16* p) {
    u32x4 v = *reinterpret_cast<const u32x4*>(p);
    return __builtin_bit_cast(b16x8, v);
}

__device__ __forceinline__ int pk_fp8x4(float a, float b, float c, float d) {
    int r = __builtin_amdgcn_cvt_pk_fp8_f32(a, b, 0, false);
    r = __builtin_amdgcn_cvt_pk_fp8_f32(c, d, r, true);
    return r;
}

__device__ __forceinline__ long as_long(u32x2 v) { return __builtin_bit_cast(long, v); }

__device__ __forceinline__ i32x8 cat8(u32x4 a, u32x4 b) {
    i32x8 r;
    r[0] = (int)a.x; r[1] = (int)a.y; r[2] = (int)a.z; r[3] = (int)a.w;
    r[4] = (int)b.x; r[5] = (int)b.y; r[6] = (int)b.z; r[7] = (int)b.w;
    return r;
}

// MX-scaled fp8 MFMA with unit scales (E8M0 127 = 1.0): plain fp8 GEMM at 2x rate.
__device__ __forceinline__ f32x4 mfma_qk128(i32x8 a, i32x8 b, f32x4 c) {
    return __builtin_amdgcn_mfma_scale_f32_16x16x128_f8f6f4(a, b, c, 0, 0, 0, 127, 0, 127);
}

// lane^16 within each 32-lane group (BitMode: xor=16, and=0x1F) — pure
// permutation through the LDS crossbar: zero bank conflicts.
__device__ __forceinline__ u32 swz16(u32 v) {
    return (u32)__builtin_amdgcn_ds_swizzle((int)v, 0x401F);
}

// v_permlane32_swap_b32: a_hi <-> b_lo. After: a=[a_lo,b_lo], b=[a_hi,b_hi].
// VALU-pipe op, no LDS involvement.
__device__ __forceinline__ void pls32(u32& a, u32& b) {
    asm("v_permlane32_swap_b32 %0, %1" : "+v"(a), "+v"(b));
}

typedef __attribute__((address_space(1))) const unsigned int* gas_p;
typedef __attribute__((address_space(3))) unsigned int* las_p;

__device__ __forceinline__ void g2l(const u8* g, u8* l) {
    __builtin_amdgcn_global_load_lds((gas_p)g, (las_p)l, 16, 0, 0);
}

__device__ __forceinline__ void g2l16(const u16* g, u16* l) {
    __builtin_amdgcn_global_load_lds((gas_p)g, (las_p)l, 16, 0, 0);
}

// ------- 2. Fold GN into QKV weights (stats inlined from gsum) + frag-major w_proj -------
__global__ void fold_w(const float* __restrict__ w_qkv, const float* __restrict__ w_proj,
                       const float* __restrict__ gamma, const float* __restrict__ beta,
                       const float* __restrict__ gsum,
                       u16* __restrict__ wqf, float* __restrict__ biasq,
                       u16* __restrict__ wpf) {
    int o = blockIdx.x;        // 0..767
    int b = blockIdx.y;        // 0..3
    int c = threadIdx.x;       // 0..255
    int g = c >> 5;
    const float inv = 1.f / ((CC / GG) * NN);
    float s  = gsum[(b * GG + g) * 2];
    float ss = gsum[(b * GG + g) * 2 + 1];
    float mu = s * inv;
    float rstd = rsqrtf(ss * inv - mu * mu + 1e-5f);
    float a  = gamma[c] * rstd;
    float bb = beta[c] - mu * a;
    float w = w_qkv[o * CC + c];
    size_t fe = ((size_t)((o >> 4) * 8 + (c >> 5)) * 64 + ((c & 31) >> 3) * 16 + (o & 15)) * 8 + (c & 7);
    wqf[(size_t)b * 768 * CC + fe] = f2bf(w * a);
    float part = w * bb;
    #pragma unroll
    for (int off = 32; off; off >>= 1) part += __shfl_down(part, off, 64);
    __shared__ float red[4];
    if ((threadIdx.x & 63) == 0) red[threadIdx.x >> 6] = part;
    __syncthreads();
    if (threadIdx.x == 0) biasq[b * 768 + o] = red[0] + red[1] + red[2] + red[3];
    if (b == 0 && o < CC) {
        float wp = w_proj[o * CC + c];
        wpf[fe] = f2bf(wp);
    }
}

// ---- 3. x [B][C][N] fp32 -> xt_frag bf16 (float4 loads); fused GN partial sums ----
__global__ void transpose_x(const float* __restrict__ x, u16* __restrict__ xtf,
                            float* __restrict__ gsum) {
    __shared__ float tile[64][65];
    __shared__ float red[4][4];
    int n0 = blockIdx.x * 64, c0 = blockIdx.y * 64, b = blockIdx.z;
    int t = threadIdx.x;
    int c4 = (t & 15) * 4;        // col base within 64-n tile
    int r0 = t >> 4;              // 0..15
    const float* xp = x + (size_t)b * CC * NN;
    float s0 = 0.f, ss0 = 0.f, s1 = 0.f, ss1 = 0.f;
    #pragma unroll
    for (int i = 0; i < 4; ++i) {
        int row = i * 16 + r0;
        float4 v = *reinterpret_cast<const float4*>(&xp[(size_t)(c0 + row) * NN + n0 + c4]);
        tile[row][c4 + 0] = v.x; tile[row][c4 + 1] = v.y;
        tile[row][c4 + 2] = v.z; tile[row][c4 + 3] = v.w;
        float s = v.x + v.y + v.z + v.w;
        float q = v.x * v.x + v.y * v.y + v.z * v.z + v.w * v.w;
        if (i < 2) { s0 += s; ss0 += q; } else { s1 += s; ss1 += q; }
    }
    #pragma unroll
    for (int off = 32; off; off >>= 1) {
        s0 += __shfl_down(s0, off, 64); ss0 += __shfl_down(ss0, off, 64);
        s1 += __shfl_down(s1, off, 64); ss1 += __shfl_down(ss1, off, 64);
    }
    int wid = t >> 6;
    if ((t & 63) == 0) { red[wid][0] = s0; red[wid][1] = ss0; red[wid][2] = s1; red[wid][3] = ss1; }
    __syncthreads();
    if (t < 2) {
        float s  = red[0][t * 2] + red[1][t * 2] + red[2][t * 2] + red[3][t * 2];
        float ss = red[0][t * 2 + 1] + red[1][t * 2 + 1] + red[2][t * 2 + 1] + red[3][t * 2 + 1];
        int g = (c0 >> 5) + t;
        atomicAdd(&gsum[(b * GG + g) * 2], s);
        atomicAdd(&gsum[(b * GG + g) * 2 + 1], ss);
    }
    int nl = t >> 2;
    int cbq = t & 3;
    int l15 = nl & 15;
    int ntile = (n0 >> 4) + (nl >> 4);
    int kk = (c0 >> 5) + (cbq >> 1);
    u16* ob = xtf + (size_t)b * NN * CC;
    #pragma unroll
    for (int g = 0; g < 4; ++g) {
        int quad = (cbq & 1) * 2 + (g >> 1);
        int j0 = (g & 1) * 4;
        u16x4 v;
        v.x = f2bf(tile[cbq * 16 + g * 4 + 0][nl]);
        v.y = f2bf(tile[cbq * 16 + g * 4 + 1][nl]);
        v.z = f2bf(tile[cbq * 16 + g * 4 + 2][nl]);
        v.w = f2bf(tile[cbq * 16 + g * 4 + 3][nl]);
        *reinterpret_cast<u16x4*>(ob + ((size_t)(ntile * 8 + kk) * 64 + quad * 16 + l15) * 8 + j0) = v;
    }
}

// ------- 4. QKV GEMM: LDS-staged B-tile, 128 o-rows/block -> fp8 q/k (K128-swz) + v -------
__global__ void __launch_bounds__(256) qkv_gemm(const u16* __restrict__ wqf,
                                                const float* __restrict__ biasq,
                                                const u16* __restrict__ xtf,
                                                u8* __restrict__ qtf, u8* __restrict__ ktf,
                                                u8* __restrict__ vvf) {
    __shared__ u16 bx[16384];     // 64 n x 256 c bf16 frag tile, 32 KB contiguous
    int b = blockIdx.z;
    int o0 = blockIdx.y * 128;    // 0,128,...,640 — never spans Q/K/V boundary
    int n0 = blockIdx.x * 64;
    int lane = threadIdx.x & 63, w = threadIdx.x >> 6;
    int l15 = lane & 15, quad = lane >> 4;
    const u16* Bg = xtf + (size_t)b * NN * CC + (size_t)n0 * 256;
    #pragma unroll
    for (int j = 0; j < 8; ++j) {
        int c = w * 8 + j;
        g2l16(Bg + (size_t)c * 512 + lane * 8, bx + (size_t)c * 512 + lane * 8);
    }
    __syncthreads();

    const u16* A = wqf + (size_t)b * 768 * CC;
    f32x4 acc[2][4] = {};
    #pragma unroll
    for (int kk = 0; kk < 8; ++kk) {
        b16x8 af[2];
        #pragma unroll
        for (int t = 0; t < 2; ++t) {
            int otile = (o0 >> 4) + w * 2 + t;
            af[t] = ldfrag(A + (size_t)(otile * 8 + kk) * 512 + lane * 8);
        }
        #pragma unroll
        for (int nt = 0; nt < 4; ++nt) {
            b16x8 bf = ldfrag(bx + (size_t)(nt * 8 + kk) * 512 + lane * 8);
            acc[0][nt] = __builtin_amdgcn_mfma_f32_16x16x32_bf16(af[0], bf, acc[0][nt], 0, 0, 0);
            acc[1][nt] = __builtin_amdgcn_mfma_f32_16x16x32_bf16(af[1], bf, acc[1][nt], 0, 0, 0);
        }
    }
    #pragma unroll
    for (int t = 0; t < 2; ++t) {
        int o_base = o0 + (w * 2 + t) * 16 + quad * 4;
        float bias[4];
        #pragma unroll
        for (int r = 0; r < 4; ++r) bias[r] = biasq[b * 768 + o_base + r];
        if (o0 < 512) {
            int oloc = (o0 < 256) ? o_base : (o_base - 256);
            u8* dst = ((o0 < 256) ? qtf : ktf) + (size_t)b * NN * CC;
            #pragma unroll
            for (int nt = 0; nt < 4; ++nt) {
                int n = n0 + nt * 16 + l15;
                int pk = pk_fp8x4(acc[t][nt][0] + bias[0], acc[t][nt][1] + bias[1],
                                  acc[t][nt][2] + bias[2], acc[t][nt][3] + bias[3]);
                // K128-frag layout + XOR swizzle: physical in-row byte =
                //   (c&127) ^ ((row&7)<<4)  (u32 stays 4B-aligned in its 16B slot)
                size_t addr = (size_t)(n >> 4) * 4096 + (size_t)(oloc >> 7) * 2048
                            + (size_t)(n & 15) * 128
                            + (size_t)((oloc & 127) ^ ((n & 7) << 4));
                *reinterpret_cast<u32*>(dst + addr) = (u32)pk;
            }
        } else {
            int cb = o_base - 512;
            u8* dst = vvf + (size_t)b * NN * CC;
            #pragma unroll
            for (int nt = 0; nt < 4; ++nt) {
                int kv = n0 + nt * 16 + l15;
                int pk = pk_fp8x4(acc[t][nt][0] + bias[0], acc[t][nt][1] + bias[1],
                                  acc[t][nt][2] + bias[2], acc[t][nt][3] + bias[3]);
                size_t base = (size_t)((kv >> 5) * 8 + (cb >> 5)) * 1024
                            + ((kv & 31) >> 3) * 256 + ((cb >> 4) & 1) * 8 + (kv & 7);
                #pragma unroll
                for (int r = 0; r < 4; ++r)
                    dst[base + ((cb & 15) + r) * 16] = (u8)(pk >> (r * 8));
            }
        }
    }
}

// ----- 5. Flash: QK^T via MX-scaled K=128 MFMA (unit scales, 2x fp8 rate): 4 MFMAs -----
// ----- per 32-kv iter. K/Q layout XOR-swizzled -> conflict-free ds_read (R8 had a  -----
// ----- 16-way conflict here, 12.6M cycles). Softmax/exchange/PV/po verbatim R7.    -----
// ----- TKV=32, 4-wave blocks, 4 barrier groups/CU.                                 -----
__global__ void __launch_bounds__(256, 4) flash(const u8* __restrict__ qtf,
                                                const u8* __restrict__ ktf,
                                                const u8* __restrict__ vvf,
                                                u16* __restrict__ po,
                                                float* __restrict__ lp) {
    __shared__ u8 kbuf[2][8192];
    __shared__ u8 vbuf[2][8192];
    int lin = blockIdx.x;
    int chunk = lin & 15;
    int nblk = lin >> 4;                  // 0..63
    int b = chunk >> 2, sp = chunk & 3;
    int lane = threadIdx.x & 63, w = threadIdx.x >> 6;   // w 0..3
    int l15 = lane & 15, quad = lane >> 4;
    int ntile = nblk * 4 + w;             // this wave's 16 q rows (0..255)
    const u8* kb8 = ktf + (size_t)b * NN * CC;
    const u8* vb8 = vvf + (size_t)b * NN * CC;
    const bool qodd = (quad & 1) != 0;
    // swizzled in-row offsets for the two 16B halves of this lane's MX block
    const int swz = (l15 & 7) << 4;
    const int off0 = (quad * 32) ^ swz;
    const int off1 = (quad * 32 + 16) ^ swz;

    // Q: two K=128 B-frags (col=q=l15, k=c=quad*32+j within each 128-c chunk)
    i32x8 qop[2];
    {
        const u8* qp = qtf + (size_t)b * NN * CC + (size_t)ntile * 4096
                     + (size_t)l15 * 128;
        u32x4 q0 = *reinterpret_cast<const u32x4*>(qp + off0);
        u32x4 q1 = *reinterpret_cast<const u32x4*>(qp + off1);
        u32x4 q2 = *reinterpret_cast<const u32x4*>(qp + 2048 + off0);
        u32x4 q3 = *reinterpret_cast<const u32x4*>(qp + 2048 + off1);
        qop[0] = cat8(q0, q1);
        qop[1] = cat8(q2, q3);
    }

    f32x4 acco[16] = {};
    f32x4 accs[2];
    const f32x4 zz = {0.f, 0.f, 0.f, 0.f};
    float lsum = 0.f;

    const int m_beg = sp * (NN / SPLITS);

    auto stage_k = [&](int buf, int m0) {
        const u8* ks = kb8 + ((size_t)m0 << 8);
        #pragma unroll
        for (int j = 0; j < 2; ++j) {
            int idx = w * 2 + j;          // 0..7 (8 KB tile)
            g2l(ks + idx * 1024 + lane * 16, &kbuf[buf][idx * 1024]);
        }
    };
    auto stage_v = [&](int buf, int m0) {
        const u8* vs = vb8 + ((size_t)m0 << 8);
        #pragma unroll
        for (int j = 0; j < 2; ++j) {
            int idx = w * 2 + j;          // 0..7 (8 KB tile)
            g2l(vs + idx * 1024 + lane * 16, &vbuf[buf][idx * 1024]);
        }
    };
    // QK over 32 kv: 2 kv-tiles x 2 K=128 MFMAs (A = K-frag, B = Q-frag, swapped)
    auto qk_tile = [&](const u8* kc) {
        __builtin_amdgcn_s_setprio(1);
        const u8* kp = kc + (size_t)l15 * 128;
        #pragma unroll
        for (int mm = 0; mm < 2; ++mm) {
            f32x4 acc = zz;
            #pragma unroll
            for (int cc = 0; cc < 2; ++cc) {
                const u8* p = kp + mm * 4096 + cc * 2048;
                u32x4 k0 = *reinterpret_cast<const u32x4*>(p + off0);
                u32x4 k1 = *reinterpret_cast<const u32x4*>(p + off1);
                acc = mfma_qk128(cat8(k0, k1), qop[cc], acc);
            }
            accs[mm] = acc;
        }
        __builtin_amdgcn_s_setprio(0);
    };
    auto exch = [&](int pa, int pb) -> long {
        u32 a = (u32)pa, bm = (u32)pb;
        u32 ax = swz16(a), bx = swz16(bm);
        pls32(a, bm);    // a=[a_lo,b_lo], bm=[a_hi,b_hi]
        pls32(ax, bx);   // ax=[ax_lo,bx_lo], bx=[ax_hi,bx_hi]
        u32 blo = qodd ? bx : a;
        u32 bhi = qodd ? bm : ax;
        return as_long(u32x2{blo, bhi});   // P^T frag: col=q=l15, k=kv=quad*8+j
    };

    // prologue: K0->k0, V0->v0, K1->k1; QK(0) in its own barrier window
    stage_k(0, m_beg);
    stage_v(0, m_beg);
    stage_k(1, m_beg + TKV);
    __syncthreads();
    qk_tile(&kbuf[0][0]);
    __syncthreads();

    for (int it = 0; it < ITERS; ++it) {
        int cur = it & 1;
        // softmax of S_it (accs dead after pk extraction)
        int pk[2];
        #pragma unroll
        for (int mm = 0; mm < 2; ++mm) {
            float e0 = exp2_raw(fmaf(accs[mm][0], QS, -FMAX));
            float e1 = exp2_raw(fmaf(accs[mm][1], QS, -FMAX));
            float e2 = exp2_raw(fmaf(accs[mm][2], QS, -FMAX));
            float e3 = exp2_raw(fmaf(accs[mm][3], QS, -FMAX));
            lsum += (e0 + e1) + (e2 + e3);
            pk[mm] = pk_fp8x4(e0, e1, e2, e3);
        }
        // QK(it+1): MFMA pipe refills while exchange/stage below issues
        if (it + 1 < ITERS) qk_tile(&kbuf[cur ^ 1][0]);
        // prefetch: K two tiles ahead, V one tile ahead
        if (it + 2 < ITERS) stage_k(cur, m_beg + (it + 2) * TKV);
        if (it + 1 < ITERS) stage_v(cur ^ 1, m_beg + (it + 1) * TKV);
        // exchange + PV(it)  (K=32 fp8 path, unchanged)
        const u8* vc = &vbuf[cur][0];
        long bop = exch(pk[0], pk[1]);
        __builtin_amdgcn_s_setprio(1);
        #pragma unroll
        for (int c2 = 0; c2 < 8; ++c2) {
            u32x4 vf = *reinterpret_cast<const u32x4*>(vc + (size_t)c2 * 1024 + lane * 16);
            acco[c2 * 2]     = __builtin_amdgcn_mfma_f32_16x16x32_fp8_fp8(
                as_long(u32x2{vf.x, vf.y}), bop, acco[c2 * 2], 0, 0, 0);
            acco[c2 * 2 + 1] = __builtin_amdgcn_mfma_f32_16x16x32_fp8_fp8(
                as_long(u32x2{vf.z, vf.w}), bop, acco[c2 * 2 + 1], 0, 0, 0);
        }
        __builtin_amdgcn_s_setprio(0);
        __syncthreads();
    }
    // epilogue: same store addresses; semantic O[q=l15][c = ct*16 + quad*4 + r]
    u16* pochunk = po + ((size_t)(sp * BB + b) * 256 + ntile) * 4096;
    #pragma unroll
    for (int ct = 0; ct < 16; ++ct) {
        u32x2 st;
        st.x = pack_bf2(acco[ct][0], acco[ct][1]);
        st.y = pack_bf2(acco[ct][2], acco[ct][3]);
        *reinterpret_cast<u32x2*>(pochunk + (size_t)(ct * 64 + quad * 16 + l15) * 4) = st;
    }
    // l[q]: quad-partitioned partials -> butterfly over quads
    lsum += __shfl_xor(lsum, 16, 64);
    lsum += __shfl_xor(lsum, 32, 64);
    if (lane < 16)
        lp[(size_t)(sp * BB + b) * NN + ntile * 16 + l15] = lsum;
}

// ------- 6. Fused proj: combine po/lp -> LDS bf16 frags, GEMM, + bias + residual -------
__global__ void __launch_bounds__(512) proj(const u16* __restrict__ wpf,
                                            const float* __restrict__ b_proj,
                                            const u16* __restrict__ po,
                                            const float* __restrict__ lp,
                                            const float* __restrict__ x,
                                            float* __restrict__ out) {
    __shared__ u16 bO[16384];      // 64 n x 256 c bf16 frag-major (local ntile-major)
    int b = blockIdx.y, n0 = blockIdx.x * 64;
    int t = threadIdx.x;
    // phase 1: combine 4 splits of po into bO (po layout: O[q=l15][c=ct*16+quad*4+r])
    {
        int u = t & 127, ntl = t >> 7;    // ntl 0..3
        int nb = (n0 >> 4) + ntl;
        int a = u & 7;                    // n pair: rows 2a, 2a+1 within 16-tile
        int cblk = u >> 3;                // 0..15 -> c = cblk*16 + cc
        float accn[2][16] = {};
        float lsum2[2] = {};
        #pragma unroll
        for (int s = 0; s < SPLITS; ++s) {
            const u16* src = po + (((size_t)(s * BB + b) * 256 + nb) * 4096)
                           + cblk * 256 + a * 8;
            #pragma unroll
            for (int q4 = 0; q4 < 4; ++q4) {
                u16 s16[8];
                *reinterpret_cast<u32x4*>(s16) = *reinterpret_cast<const u32x4*>(src + q4 * 64);
                #pragma unroll
                for (int k = 0; k < 8; ++k)
                    accn[k >> 2][q4 * 4 + (k & 3)] += bf2f(s16[k]);
            }
            lsum2[0] += lp[(size_t)(s * BB + b) * NN + nb * 16 + a * 2];
            lsum2[1] += lp[(size_t)(s * BB + b) * NN + nb * 16 + a * 2 + 1];
        }
        #pragma unroll
        for (int nsel = 0; nsel < 2; ++nsel) {
            float inv = 1.f / lsum2[nsel];
            int row = a * 2 + nsel;
            #pragma unroll
            for (int h = 0; h < 2; ++h) {
                u16 outv[8];
                #pragma unroll
                for (int j = 0; j < 8; ++j) outv[j] = f2bf(accn[nsel][h * 8 + j] * inv);
                int kk = cblk >> 1, quad_f = (cblk & 1) * 2 + h;
                size_t off = ((size_t)(ntl * 8 + kk) * 64 + quad_f * 16 + row) * 8;
                *reinterpret_cast<u32x4*>(bO + off) = *reinterpret_cast<const u32x4*>(outv);
            }
        }
    }
    __syncthreads();
    // phase 2: GEMM — 8 waves x 2 o-tiles = full 256 outputs
    int lane = t & 63, w = t >> 6;
    int l15 = lane & 15, quad = lane >> 4;
    f32x4 acc2[2][4] = {};
    #pragma unroll
    for (int kk = 0; kk < 8; ++kk) {
        b16x8 af[2];
        #pragma unroll
        for (int tt = 0; tt < 2; ++tt) {
            int otile = w * 2 + tt;
            af[tt] = ldfrag(wpf + (size_t)(otile * 8 + kk) * 512 + lane * 8);
        }
        #pragma unroll
        for (int nt = 0; nt < 4; ++nt) {
            b16x8 bf = ldfrag(bO + (size_t)(nt * 8 + kk) * 512 + lane * 8);
            acc2[0][nt] = __builtin_amdgcn_mfma_f32_16x16x32_bf16(af[0], bf, acc2[0][nt], 0, 0, 0);
            acc2[1][nt] = __builtin_amdgcn_mfma_f32_16x16x32_bf16(af[1], bf, acc2[1][nt], 0, 0, 0);
        }
    }
    #pragma unroll
    for (int tt = 0; tt < 2; ++tt) {
        int o_base = (w * 2 + tt) * 16 + quad * 4;
        #pragma unroll
        for (int nt = 0; nt < 4; ++nt) {
            int n = n0 + nt * 16 + l15;
            #pragma unroll
            for (int r = 0; r < 4; ++r) {
                int o = o_base + r;
                size_t idx = ((size_t)(b * CC + o)) * NN + n;
                out[idx] = acc2[tt][nt][r] + b_proj[o] + x[idx];
            }
        }
    }
}

extern "C" void kernel_launch(void* const* d_in, const int* in_sizes, int n_in,
                              void* d_out, int out_size, void* d_ws, size_t ws_size,
                              hipStream_t stream) {
    const float* x      = (const float*)d_in[0];
    const float* gamma  = (const float*)d_in[1];
    const float* beta   = (const float*)d_in[2];
    const float* w_qkv  = (const float*)d_in[3];
    const float* w_proj = (const float*)d_in[4];
    const float* b_proj = (const float*)d_in[5];
    float* out = (float*)d_out;

    char* p = (char*)d_ws;
    float* gsum  = (float*)p; p += 256;
    float* biasq = (float*)p; p += (size_t)BB * 768 * sizeof(float);
    u16* wqf = (u16*)p; p += (size_t)BB * 768 * CC * 2;
    u16* wpf = (u16*)p; p += (size_t)CC * CC * 2;
    u16* xtf = (u16*)p; p += (size_t)BB * NN * CC * 2;
    u8* qtf8 = (u8*)p; p += (size_t)BB * NN * CC;
    u8* ktf8 = (u8*)p; p += (size_t)BB * NN * CC;
    u8* vvf8 = (u8*)p; p += (size_t)BB * NN * CC;
    u16* po = (u16*)p; p += (size_t)SPLITS * BB * NN * CC * 2;
    float* lp = (float*)p; p += (size_t)SPLITS * BB * NN * sizeof(float);
    (void)ws_size; (void)in_sizes; (void)n_in; (void)out_size;

    (void)hipMemsetAsync(gsum, 0, BB * GG * 2 * sizeof(float), stream);
    transpose_x<<<dim3(NN / 64, CC / 64, BB), 256, 0, stream>>>(x, xtf, gsum);
    fold_w<<<dim3(768, BB), 256, 0, stream>>>(w_qkv, w_proj, gamma, beta, gsum, wqf, biasq, wpf);
    qkv_gemm<<<dim3(NN / 64, 6, BB), 256, 0, stream>>>(wqf, biasq, xtf, qtf8, ktf8, vvf8);
    flash<<<(NN / 64) * SPLITS * BB, 256, 0, stream>>>(qtf8, ktf8, vvf8, po, lp);
    proj<<<dim3(NN / 64, BB), 512, 0, stream>>>(wpf, b_proj, po, lp, x, out);
}

// Round 10
// 167.113 us; speedup vs baseline: 1.0454x; 1.0262x over previous
//
#include <hip/hip_runtime.h>
#include <hip/hip_bf16.h>

#define BB 4
#define CC 256
#define NN 4096
#define GG 8
#define SPLITS 4
#define TKV 32
#define ITERS (NN / SPLITS / TKV)

typedef unsigned char u8;
typedef unsigned short u16;
typedef unsigned int u32;
typedef __bf16 b16x8 __attribute__((ext_vector_type(8)));
typedef float f32x4 __attribute__((ext_vector_type(4)));
typedef u32 u32x4 __attribute__((ext_vector_type(4)));
typedef u32 u32x2 __attribute__((ext_vector_type(2)));
typedef u16 u16x4 __attribute__((ext_vector_type(4)));
typedef int i32x8 __attribute__((ext_vector_type(8)));

// softmax: P' = exp2(S_raw * QS - FMAX); QS = C^-0.5 * log2(e). FMAX=8 keeps
// P' inside e4m3's normal range. l,O scale-invariant.
#define QS 0.09016844005556021f
#define FMAX 8.0f

// bf16 fragment chunk (512 u16): elem(row,col32) = (quad(col32>>3)*16+row)*8+(col32&7)
// fp8 Q/K chunk (K=128 FRAG-LINEAR layout for mfma_scale 16x16x128):
//   per 16-row x 256-c = 4KB: four 1KB sub-chunks [cc = c>>7][h = (c>>4)&1];
//   within: addr = lane*16 + (c&15), lane = ((c&127)>>5)*16 + row.
//   Flash reads are base + lane*16 over contiguous 1KB — the measured
//   conflict-free pattern (R9's row-strided XOR layout still had 4 cyc/read).
//   Lane (row=l15, quad) gets k = quad*32 + (h*16 + byte) — one MX block/lane.
// fp8 V superchunk (1024 B, 32 c x 32 kv):
//   addr(c,kv) = ((kv&31)>>3)*256 + (c&15)*16 + ((c>>4)&1)*8 + (kv&7)
// po (swapped-PV flash): per (split,b,ntile) chunk of 4096 u16:
//   u16 idx = (ct*64 + quad*16 + l15)*4 + r  ->  O[q=l15][c = ct*16 + quad*4 + r]

__device__ __forceinline__ u16 f2bf(float f) {
    u32 u = __builtin_bit_cast(u32, f);
    u = (u + 0x7FFFu + ((u >> 16) & 1u)) >> 16;
    return (u16)u;
}

__device__ __forceinline__ float bf2f(u16 h) {
    return __builtin_bit_cast(float, (u32)h << 16);
}

__device__ __forceinline__ u32 pack_bf2(float a, float b) {
    float2 f; f.x = a; f.y = b;
    __hip_bfloat162 h = __float22bfloat162_rn(f);
    u32 r;
    __builtin_memcpy(&r, &h, 4);
    return r;
}

__device__ __forceinline__ float exp2_raw(float x) {
#if __has_builtin(__builtin_amdgcn_exp2f)
    return __builtin_amdgcn_exp2f(x);
#else
    float r;
    asm("v_exp_f32 %0, %1" : "=v"(r) : "v"(x));
    return r;
#endif
}

__device__ __forceinline__ b16x8 ldfrag(const u16* p) {
    u32x4 v = *reinterpret_cast<const u32x4*>(p);
    return __builtin_bit_cast(b16x8, v);
}

__device__ __forceinline__ int pk_fp8x4(float a, float b, float c, float d) {
    int r = __builtin_amdgcn_cvt_pk_fp8_f32(a, b, 0, false);
    r = __builtin_amdgcn_cvt_pk_fp8_f32(c, d, r, true);
    return r;
}

__device__ __forceinline__ long as_long(u32x2 v) { return __builtin_bit_cast(long, v); }

__device__ __forceinline__ i32x8 cat8(u32x4 a, u32x4 b) {
    i32x8 r;
    r[0] = (int)a.x; r[1] = (int)a.y; r[2] = (int)a.z; r[3] = (int)a.w;
    r[4] = (int)b.x; r[5] = (int)b.y; r[6] = (int)b.z; r[7] = (int)b.w;
    return r;
}

// MX-scaled fp8 MFMA with unit scales (E8M0 127 = 1.0): plain fp8 GEMM at 2x rate.
__device__ __forceinline__ f32x4 mfma_qk128(i32x8 a, i32x8 b, f32x4 c) {
    return __builtin_amdgcn_mfma_scale_f32_16x16x128_f8f6f4(a, b, c, 0, 0, 0, 127, 0, 127);
}

// lane^16 within each 32-lane group (BitMode: xor=16, and=0x1F) — pure
// permutation through the LDS crossbar: zero bank conflicts.
__device__ __forceinline__ u32 swz16(u32 v) {
    return (u32)__builtin_amdgcn_ds_swizzle((int)v, 0x401F);
}

// v_permlane32_swap_b32: a_hi <-> b_lo. After: a=[a_lo,b_lo], b=[a_hi,b_hi].
// VALU-pipe op, no LDS involvement.
__device__ __forceinline__ void pls32(u32& a, u32& b) {
    asm("v_permlane32_swap_b32 %0, %1" : "+v"(a), "+v"(b));
}

typedef __attribute__((address_space(1))) const unsigned int* gas_p;
typedef __attribute__((address_space(3))) unsigned int* las_p;

__device__ __forceinline__ void g2l(const u8* g, u8* l) {
    __builtin_amdgcn_global_load_lds((gas_p)g, (las_p)l, 16, 0, 0);
}

__device__ __forceinline__ void g2l16(const u16* g, u16* l) {
    __builtin_amdgcn_global_load_lds((gas_p)g, (las_p)l, 16, 0, 0);
}

// ------- 2. Fold GN into QKV weights (stats inlined from gsum) + frag-major w_proj -------
__global__ void fold_w(const float* __restrict__ w_qkv, const float* __restrict__ w_proj,
                       const float* __restrict__ gamma, const float* __restrict__ beta,
                       const float* __restrict__ gsum,
                       u16* __restrict__ wqf, float* __restrict__ biasq,
                       u16* __restrict__ wpf) {
    int o = blockIdx.x;        // 0..767
    int b = blockIdx.y;        // 0..3
    int c = threadIdx.x;       // 0..255
    int g = c >> 5;
    const float inv = 1.f / ((CC / GG) * NN);
    float s  = gsum[(b * GG + g) * 2];
    float ss = gsum[(b * GG + g) * 2 + 1];
    float mu = s * inv;
    float rstd = rsqrtf(ss * inv - mu * mu + 1e-5f);
    float a  = gamma[c] * rstd;
    float bb = beta[c] - mu * a;
    float w = w_qkv[o * CC + c];
    size_t fe = ((size_t)((o >> 4) * 8 + (c >> 5)) * 64 + ((c & 31) >> 3) * 16 + (o & 15)) * 8 + (c & 7);
    wqf[(size_t)b * 768 * CC + fe] = f2bf(w * a);
    float part = w * bb;
    #pragma unroll
    for (int off = 32; off; off >>= 1) part += __shfl_down(part, off, 64);
    __shared__ float red[4];
    if ((threadIdx.x & 63) == 0) red[threadIdx.x >> 6] = part;
    __syncthreads();
    if (threadIdx.x == 0) biasq[b * 768 + o] = red[0] + red[1] + red[2] + red[3];
    if (b == 0 && o < CC) {
        float wp = w_proj[o * CC + c];
        wpf[fe] = f2bf(wp);
    }
}

// ---- 3. x [B][C][N] fp32 -> xt_frag bf16 (float4 loads); fused GN partial sums ----
__global__ void transpose_x(const float* __restrict__ x, u16* __restrict__ xtf,
                            float* __restrict__ gsum) {
    __shared__ float tile[64][65];
    __shared__ float red[4][4];
    int n0 = blockIdx.x * 64, c0 = blockIdx.y * 64, b = blockIdx.z;
    int t = threadIdx.x;
    int c4 = (t & 15) * 4;        // col base within 64-n tile
    int r0 = t >> 4;              // 0..15
    const float* xp = x + (size_t)b * CC * NN;
    float s0 = 0.f, ss0 = 0.f, s1 = 0.f, ss1 = 0.f;
    #pragma unroll
    for (int i = 0; i < 4; ++i) {
        int row = i * 16 + r0;
        float4 v = *reinterpret_cast<const float4*>(&xp[(size_t)(c0 + row) * NN + n0 + c4]);
        tile[row][c4 + 0] = v.x; tile[row][c4 + 1] = v.y;
        tile[row][c4 + 2] = v.z; tile[row][c4 + 3] = v.w;
        float s = v.x + v.y + v.z + v.w;
        float q = v.x * v.x + v.y * v.y + v.z * v.z + v.w * v.w;
        if (i < 2) { s0 += s; ss0 += q; } else { s1 += s; ss1 += q; }
    }
    #pragma unroll
    for (int off = 32; off; off >>= 1) {
        s0 += __shfl_down(s0, off, 64); ss0 += __shfl_down(ss0, off, 64);
        s1 += __shfl_down(s1, off, 64); ss1 += __shfl_down(ss1, off, 64);
    }
    int wid = t >> 6;
    if ((t & 63) == 0) { red[wid][0] = s0; red[wid][1] = ss0; red[wid][2] = s1; red[wid][3] = ss1; }
    __syncthreads();
    if (t < 2) {
        float s  = red[0][t * 2] + red[1][t * 2] + red[2][t * 2] + red[3][t * 2];
        float ss = red[0][t * 2 + 1] + red[1][t * 2 + 1] + red[2][t * 2 + 1] + red[3][t * 2 + 1];
        int g = (c0 >> 5) + t;
        atomicAdd(&gsum[(b * GG + g) * 2], s);
        atomicAdd(&gsum[(b * GG + g) * 2 + 1], ss);
    }
    int nl = t >> 2;
    int cbq = t & 3;
    int l15 = nl & 15;
    int ntile = (n0 >> 4) + (nl >> 4);
    int kk = (c0 >> 5) + (cbq >> 1);
    u16* ob = xtf + (size_t)b * NN * CC;
    #pragma unroll
    for (int g = 0; g < 4; ++g) {
        int quad = (cbq & 1) * 2 + (g >> 1);
        int j0 = (g & 1) * 4;
        u16x4 v;
        v.x = f2bf(tile[cbq * 16 + g * 4 + 0][nl]);
        v.y = f2bf(tile[cbq * 16 + g * 4 + 1][nl]);
        v.z = f2bf(tile[cbq * 16 + g * 4 + 2][nl]);
        v.w = f2bf(tile[cbq * 16 + g * 4 + 3][nl]);
        *reinterpret_cast<u16x4*>(ob + ((size_t)(ntile * 8 + kk) * 64 + quad * 16 + l15) * 8 + j0) = v;
    }
}

// ------- 4. QKV GEMM: LDS-staged B-tile, 128 o-rows/block -> fp8 q/k (frag-linear) + v -------
__global__ void __launch_bounds__(256) qkv_gemm(const u16* __restrict__ wqf,
                                                const float* __restrict__ biasq,
                                                const u16* __restrict__ xtf,
                                                u8* __restrict__ qtf, u8* __restrict__ ktf,
                                                u8* __restrict__ vvf) {
    __shared__ u16 bx[16384];     // 64 n x 256 c bf16 frag tile, 32 KB contiguous
    int b = blockIdx.z;
    int o0 = blockIdx.y * 128;    // 0,128,...,640 — never spans Q/K/V boundary
    int n0 = blockIdx.x * 64;
    int lane = threadIdx.x & 63, w = threadIdx.x >> 6;
    int l15 = lane & 15, quad = lane >> 4;
    const u16* Bg = xtf + (size_t)b * NN * CC + (size_t)n0 * 256;
    #pragma unroll
    for (int j = 0; j < 8; ++j) {
        int c = w * 8 + j;
        g2l16(Bg + (size_t)c * 512 + lane * 8, bx + (size_t)c * 512 + lane * 8);
    }
    __syncthreads();

    const u16* A = wqf + (size_t)b * 768 * CC;
    f32x4 acc[2][4] = {};
    #pragma unroll
    for (int kk = 0; kk < 8; ++kk) {
        b16x8 af[2];
        #pragma unroll
        for (int t = 0; t < 2; ++t) {
            int otile = (o0 >> 4) + w * 2 + t;
            af[t] = ldfrag(A + (size_t)(otile * 8 + kk) * 512 + lane * 8);
        }
        #pragma unroll
        for (int nt = 0; nt < 4; ++nt) {
            b16x8 bf = ldfrag(bx + (size_t)(nt * 8 + kk) * 512 + lane * 8);
            acc[0][nt] = __builtin_amdgcn_mfma_f32_16x16x32_bf16(af[0], bf, acc[0][nt], 0, 0, 0);
            acc[1][nt] = __builtin_amdgcn_mfma_f32_16x16x32_bf16(af[1], bf, acc[1][nt], 0, 0, 0);
        }
    }
    #pragma unroll
    for (int t = 0; t < 2; ++t) {
        int o_base = o0 + (w * 2 + t) * 16 + quad * 4;
        float bias[4];
        #pragma unroll
        for (int r = 0; r < 4; ++r) bias[r] = biasq[b * 768 + o_base + r];
        if (o0 < 512) {
            int oloc = (o0 < 256) ? o_base : (o_base - 256);
            u8* dst = ((o0 < 256) ? qtf : ktf) + (size_t)b * NN * CC;
            #pragma unroll
            for (int nt = 0; nt < 4; ++nt) {
                int n = n0 + nt * 16 + l15;
                int pk = pk_fp8x4(acc[t][nt][0] + bias[0], acc[t][nt][1] + bias[1],
                                  acc[t][nt][2] + bias[2], acc[t][nt][3] + bias[3]);
                // frag-linear K128 layout: 4KB/16-row chunk, 1KB sub-chunk
                // [cc = c>>7][h = (c>>4)&1], within: lane*16 + (c&15),
                // lane = ((c&127)>>5)*16 + row. oloc%4==0 -> one aligned u32.
                size_t addr = (size_t)(n >> 4) * 4096 + (size_t)(oloc >> 7) * 2048
                            + (size_t)((oloc >> 4) & 1) * 1024
                            + (size_t)(((oloc & 127) >> 5) * 16 + (n & 15)) * 16
                            + (oloc & 15);
                *reinterpret_cast<u32*>(dst + addr) = (u32)pk;
            }
        } else {
            int cb = o_base - 512;
            u8* dst = vvf + (size_t)b * NN * CC;
            #pragma unroll
            for (int nt = 0; nt < 4; ++nt) {
                int kv = n0 + nt * 16 + l15;
                int pk = pk_fp8x4(acc[t][nt][0] + bias[0], acc[t][nt][1] + bias[1],
                                  acc[t][nt][2] + bias[2], acc[t][nt][3] + bias[3]);
                size_t base = (size_t)((kv >> 5) * 8 + (cb >> 5)) * 1024
                            + ((kv & 31) >> 3) * 256 + ((cb >> 4) & 1) * 8 + (kv & 7);
                #pragma unroll
                for (int r = 0; r < 4; ++r)
                    dst[base + ((cb & 15) + r) * 16] = (u8)(pk >> (r * 8));
            }
        }
    }
}

// ----- 5. Flash: QK^T via MX-scaled K=128 MFMA (unit scales, 2x fp8 rate): 4 MFMAs -----
// ----- per 32-kv iter. K/Q frag-linear layout -> all LDS reads are base+lane*16    -----
// ----- over contiguous 1KB (the measured-conflict-free pattern; R9's XOR layout    -----
// ----- still cost 4 cyc/read). Softmax/exchange/PV/po verbatim R7.                 -----
// ----- TKV=32, 4-wave blocks, 4 barrier groups/CU.                                 -----
__global__ void __launch_bounds__(256, 4) flash(const u8* __restrict__ qtf,
                                                const u8* __restrict__ ktf,
                                                const u8* __restrict__ vvf,
                                                u16* __restrict__ po,
                                                float* __restrict__ lp) {
    __shared__ u8 kbuf[2][8192];
    __shared__ u8 vbuf[2][8192];
    int lin = blockIdx.x;
    int chunk = lin & 15;
    int nblk = lin >> 4;                  // 0..63
    int b = chunk >> 2, sp = chunk & 3;
    int lane = threadIdx.x & 63, w = threadIdx.x >> 6;   // w 0..3
    int l15 = lane & 15, quad = lane >> 4;
    int ntile = nblk * 4 + w;             // this wave's 16 q rows (0..255)
    const u8* kb8 = ktf + (size_t)b * NN * CC;
    const u8* vb8 = vvf + (size_t)b * NN * CC;
    const bool qodd = (quad & 1) != 0;

    // Q: two K=128 B-frags (col=q=l15, k=c=quad*32+j); frag-linear loads
    i32x8 qop[2];
    {
        const u8* qp = qtf + (size_t)b * NN * CC + (size_t)ntile * 4096
                     + (size_t)lane * 16;
        u32x4 q0 = *reinterpret_cast<const u32x4*>(qp);
        u32x4 q1 = *reinterpret_cast<const u32x4*>(qp + 1024);
        u32x4 q2 = *reinterpret_cast<const u32x4*>(qp + 2048);
        u32x4 q3 = *reinterpret_cast<const u32x4*>(qp + 2048 + 1024);
        qop[0] = cat8(q0, q1);
        qop[1] = cat8(q2, q3);
    }

    f32x4 acco[16] = {};
    f32x4 accs[2];
    const f32x4 zz = {0.f, 0.f, 0.f, 0.f};
    float lsum = 0.f;

    const int m_beg = sp * (NN / SPLITS);

    auto stage_k = [&](int buf, int m0) {
        const u8* ks = kb8 + ((size_t)m0 << 8);
        #pragma unroll
        for (int j = 0; j < 2; ++j) {
            int idx = w * 2 + j;          // 0..7 (8 KB tile)
            g2l(ks + idx * 1024 + lane * 16, &kbuf[buf][idx * 1024]);
        }
    };
    auto stage_v = [&](int buf, int m0) {
        const u8* vs = vb8 + ((size_t)m0 << 8);
        #pragma unroll
        for (int j = 0; j < 2; ++j) {
            int idx = w * 2 + j;          // 0..7 (8 KB tile)
            g2l(vs + idx * 1024 + lane * 16, &vbuf[buf][idx * 1024]);
        }
    };
    // QK over 32 kv: 2 kv-tiles x 2 K=128 MFMAs (A = K-frag, B = Q-frag, swapped)
    auto qk_tile = [&](const u8* kc) {
        __builtin_amdgcn_s_setprio(1);
        const u8* kp = kc + (size_t)lane * 16;
        #pragma unroll
        for (int mm = 0; mm < 2; ++mm) {
            f32x4 acc = zz;
            #pragma unroll
            for (int cc = 0; cc < 2; ++cc) {
                const u8* p = kp + mm * 4096 + cc * 2048;
                u32x4 k0 = *reinterpret_cast<const u32x4*>(p);
                u32x4 k1 = *reinterpret_cast<const u32x4*>(p + 1024);
                acc = mfma_qk128(cat8(k0, k1), qop[cc], acc);
            }
            accs[mm] = acc;
        }
        __builtin_amdgcn_s_setprio(0);
    };
    auto exch = [&](int pa, int pb) -> long {
        u32 a = (u32)pa, bm = (u32)pb;
        u32 ax = swz16(a), bx = swz16(bm);
        pls32(a, bm);    // a=[a_lo,b_lo], bm=[a_hi,b_hi]
        pls32(ax, bx);   // ax=[ax_lo,bx_lo], bx=[ax_hi,bx_hi]
        u32 blo = qodd ? bx : a;
        u32 bhi = qodd ? bm : ax;
        return as_long(u32x2{blo, bhi});   // P^T frag: col=q=l15, k=kv=quad*8+j
    };

    // prologue: K0->k0, V0->v0, K1->k1; QK(0) in its own barrier window
    stage_k(0, m_beg);
    stage_v(0, m_beg);
    stage_k(1, m_beg + TKV);
    __syncthreads();
    qk_tile(&kbuf[0][0]);
    __syncthreads();

    for (int it = 0; it < ITERS; ++it) {
        int cur = it & 1;
        // softmax of S_it (accs dead after pk extraction)
        int pk[2];
        #pragma unroll
        for (int mm = 0; mm < 2; ++mm) {
            float e0 = exp2_raw(fmaf(accs[mm][0], QS, -FMAX));
            float e1 = exp2_raw(fmaf(accs[mm][1], QS, -FMAX));
            float e2 = exp2_raw(fmaf(accs[mm][2], QS, -FMAX));
            float e3 = exp2_raw(fmaf(accs[mm][3], QS, -FMAX));
            lsum += (e0 + e1) + (e2 + e3);
            pk[mm] = pk_fp8x4(e0, e1, e2, e3);
        }
        // QK(it+1): MFMA pipe refills while exchange/stage below issues
        if (it + 1 < ITERS) qk_tile(&kbuf[cur ^ 1][0]);
        // prefetch: K two tiles ahead, V one tile ahead
        if (it + 2 < ITERS) stage_k(cur, m_beg + (it + 2) * TKV);
        if (it + 1 < ITERS) stage_v(cur ^ 1, m_beg + (it + 1) * TKV);
        // exchange + PV(it)  (K=32 fp8 path, unchanged)
        const u8* vc = &vbuf[cur][0];
        long bop = exch(pk[0], pk[1]);
        __builtin_amdgcn_s_setprio(1);
        #pragma unroll
        for (int c2 = 0; c2 < 8; ++c2) {
            u32x4 vf = *reinterpret_cast<const u32x4*>(vc + (size_t)c2 * 1024 + lane * 16);
            acco[c2 * 2]     = __builtin_amdgcn_mfma_f32_16x16x32_fp8_fp8(
                as_long(u32x2{vf.x, vf.y}), bop, acco[c2 * 2], 0, 0, 0);
            acco[c2 * 2 + 1] = __builtin_amdgcn_mfma_f32_16x16x32_fp8_fp8(
                as_long(u32x2{vf.z, vf.w}), bop, acco[c2 * 2 + 1], 0, 0, 0);
        }
        __builtin_amdgcn_s_setprio(0);
        __syncthreads();
    }
    // epilogue: same store addresses; semantic O[q=l15][c = ct*16 + quad*4 + r]
    u16* pochunk = po + ((size_t)(sp * BB + b) * 256 + ntile) * 4096;
    #pragma unroll
    for (int ct = 0; ct < 16; ++ct) {
        u32x2 st;
        st.x = pack_bf2(acco[ct][0], acco[ct][1]);
        st.y = pack_bf2(acco[ct][2], acco[ct][3]);
        *reinterpret_cast<u32x2*>(pochunk + (size_t)(ct * 64 + quad * 16 + l15) * 4) = st;
    }
    // l[q]: quad-partitioned partials -> butterfly over quads
    lsum += __shfl_xor(lsum, 16, 64);
    lsum += __shfl_xor(lsum, 32, 64);
    if (lane < 16)
        lp[(size_t)(sp * BB + b) * NN + ntile * 16 + l15] = lsum;
}

// ------- 6. Fused proj: combine po/lp -> LDS bf16 frags, GEMM, + bias + residual -------
__global__ void __launch_bounds__(512) proj(const u16* __restrict__ wpf,
                                            const float* __restrict__ b_proj,
                                            const u16* __restrict__ po,
                                            const float* __restrict__ lp,
                                            const float* __restrict__ x,
                                            float* __restrict__ out) {
    __shared__ u16 bO[16384];      // 64 n x 256 c bf16 frag-major (local ntile-major)
    int b = blockIdx.y, n0 = blockIdx.x * 64;
    int t = threadIdx.x;
    // phase 1: combine 4 splits of po into bO (po layout: O[q=l15][c=ct*16+quad*4+r])
    {
        int u = t & 127, ntl = t >> 7;    // ntl 0..3
        int nb = (n0 >> 4) + ntl;
        int a = u & 7;                    // n pair: rows 2a, 2a+1 within 16-tile
        int cblk = u >> 3;                // 0..15 -> c = cblk*16 + cc
        float accn[2][16] = {};
        float lsum2[2] = {};
        #pragma unroll
        for (int s = 0; s < SPLITS; ++s) {
            const u16* src = po + (((size_t)(s * BB + b) * 256 + nb) * 4096)
                           + cblk * 256 + a * 8;
            #pragma unroll
            for (int q4 = 0; q4 < 4; ++q4) {
                u16 s16[8];
                *reinterpret_cast<u32x4*>(s16) = *reinterpret_cast<const u32x4*>(src + q4 * 64);
                #pragma unroll
                for (int k = 0; k < 8; ++k)
                    accn[k >> 2][q4 * 4 + (k & 3)] += bf2f(s16[k]);
            }
            lsum2[0] += lp[(size_t)(s * BB + b) * NN + nb * 16 + a * 2];
            lsum2[1] += lp[(size_t)(s * BB + b) * NN + nb * 16 + a * 2 + 1];
        }
        #pragma unroll
        for (int nsel = 0; nsel < 2; ++nsel) {
            float inv = 1.f / lsum2[nsel];
            int row = a * 2 + nsel;
            #pragma unroll
            for (int h = 0; h < 2; ++h) {
                u16 outv[8];
                #pragma unroll
                for (int j = 0; j < 8; ++j) outv[j] = f2bf(accn[nsel][h * 8 + j] * inv);
                int kk = cblk >> 1, quad_f = (cblk & 1) * 2 + h;
                size_t off = ((size_t)(ntl * 8 + kk) * 64 + quad_f * 16 + row) * 8;
                *reinterpret_cast<u32x4*>(bO + off) = *reinterpret_cast<const u32x4*>(outv);
            }
        }
    }
    __syncthreads();
    // phase 2: GEMM — 8 waves x 2 o-tiles = full 256 outputs
    int lane = t & 63, w = t >> 6;
    int l15 = lane & 15, quad = lane >> 4;
    f32x4 acc2[2][4] = {};
    #pragma unroll
    for (int kk = 0; kk < 8; ++kk) {
        b16x8 af[2];
        #pragma unroll
        for (int tt = 0; tt < 2; ++tt) {
            int otile = w * 2 + tt;
            af[tt] = ldfrag(wpf + (size_t)(otile * 8 + kk) * 512 + lane * 8);
        }
        #pragma unroll
        for (int nt = 0; nt < 4; ++nt) {
            b16x8 bf = ldfrag(bO + (size_t)(nt * 8 + kk) * 512 + lane * 8);
            acc2[0][nt] = __builtin_amdgcn_mfma_f32_16x16x32_bf16(af[0], bf, acc2[0][nt], 0, 0, 0);
            acc2[1][nt] = __builtin_amdgcn_mfma_f32_16x16x32_bf16(af[1], bf, acc2[1][nt], 0, 0, 0);
        }
    }
    #pragma unroll
    for (int tt = 0; tt < 2; ++tt) {
        int o_base = (w * 2 + tt) * 16 + quad * 4;
        #pragma unroll
        for (int nt = 0; nt < 4; ++nt) {
            int n = n0 + nt * 16 + l15;
            #pragma unroll
            for (int r = 0; r < 4; ++r) {
                int o = o_base + r;
                size_t idx = ((size_t)(b * CC + o)) * NN + n;
                out[idx] = acc2[tt][nt][r] + b_proj[o] + x[idx];
            }
        }
    }
}

extern "C" void kernel_launch(void* const* d_in, const int* in_sizes, int n_in,
                              void* d_out, int out_size, void* d_ws, size_t ws_size,
                              hipStream_t stream) {
    const float* x      = (const float*)d_in[0];
    const float* gamma  = (const float*)d_in[1];
    const float* beta   = (const float*)d_in[2];
    const float* w_qkv  = (const float*)d_in[3];
    const float* w_proj = (const float*)d_in[4];
    const float* b_proj = (const float*)d_in[5];
    float* out = (float*)d_out;

    char* p = (char*)d_ws;
    float* gsum  = (float*)p; p += 256;
    float* biasq = (float*)p; p += (size_t)BB * 768 * sizeof(float);
    u16* wqf = (u16*)p; p += (size_t)BB * 768 * CC * 2;
    u16* wpf = (u16*)p; p += (size_t)CC * CC * 2;
    u16* xtf = (u16*)p; p += (size_t)BB * NN * CC * 2;
    u8* qtf8 = (u8*)p; p += (size_t)BB * NN * CC;
    u8* ktf8 = (u8*)p; p += (size_t)BB * NN * CC;
    u8* vvf8 = (u8*)p; p += (size_t)BB * NN * CC;
    u16* po = (u16*)p; p += (size_t)SPLITS * BB * NN * CC * 2;
    float* lp = (float*)p; p += (size_t)SPLITS * BB * NN * sizeof(float);
    (void)ws_size; (void)in_sizes; (void)n_in; (void)out_size;

    (void)hipMemsetAsync(gsum, 0, BB * GG * 2 * sizeof(float), stream);
    transpose_x<<<dim3(NN / 64, CC / 64, BB), 256, 0, stream>>>(x, xtf, gsum);
    fold_w<<<dim3(768, BB), 256, 0, stream>>>(w_qkv, w_proj, gamma, beta, gsum, wqf, biasq, wpf);
    qkv_gemm<<<dim3(NN / 64, 6, BB), 256, 0, stream>>>(wqf, biasq, xtf, qtf8, ktf8, vvf8);
    flash<<<(NN / 64) * SPLITS * BB, 256, 0, stream>>>(qtf8, ktf8, vvf8, po, lp);
    proj<<<dim3(NN / 64, BB), 512, 0, stream>>>(wpf, b_proj, po, lp, x, out);
}